// Round 1
// baseline (84.402 us; speedup 1.0000x reference)
//
#include <hip/hip_runtime.h>
#include <math.h>

#define DIM 16

// ---------------------------------------------------------------------------
// Kernel A: build the 16x16 variational unitary from params[36].
// 16 active lanes; lane c evolves column c (= circuit applied to basis |c>)
// entirely in registers. All indices compile-time via full unroll.
// Layout out: Uout[0..255] = Re(U) row-major, Uout[256..511] = Im(U).
// ---------------------------------------------------------------------------
__global__ __launch_bounds__(64) void build_unitary_kernel(
    const float* __restrict__ params, float* __restrict__ Uout) {
  __shared__ float s_c[36], s_s[36];
  const int t = threadIdx.x;
  if (t < 36) {
    const float half = params[t] * 0.5f;
    s_c[t] = cosf(half);
    s_s[t] = sinf(half);
  }
  __syncthreads();
  if (t >= DIM) return;
  const int col = t;

  float vr[DIM], vi[DIM];
#pragma unroll
  for (int k = 0; k < DIM; ++k) { vr[k] = (k == col) ? 1.0f : 0.0f; vi[k] = 0.0f; }

  int off = 0;
#pragma unroll
  for (int layer = 0; layer < 3; ++layer) {
#pragma unroll
    for (int w = 0; w < 4; ++w) {
      const int m = 1 << (3 - w);  // wire w <-> bit (3-w), big-endian
      // --- RY(params[off]) ---
      {
        const float cy = s_c[off], sy = s_s[off]; ++off;
#pragma unroll
        for (int k0 = 0; k0 < DIM; ++k0) {
          if (k0 & m) continue;
          const int k1 = k0 | m;
          const float ar = vr[k0], ai = vi[k0], br = vr[k1], bi = vi[k1];
          vr[k0] = cy * ar - sy * br;  vi[k0] = cy * ai - sy * bi;
          vr[k1] = sy * ar + cy * br;  vi[k1] = sy * ai + cy * bi;
        }
      }
      // --- RZ(params[off]) : diag(e^{-it/2}, e^{+it/2}) ---
      {
        const float cz = s_c[off], sz = s_s[off]; ++off;
#pragma unroll
        for (int k = 0; k < DIM; ++k) {
          const float sg = (k & m) ? sz : -sz;
          const float ar = vr[k], ai = vi[k];
          vr[k] = cz * ar - sg * ai;
          vi[k] = cz * ai + sg * ar;
        }
      }
      // --- RY(params[off]) ---
      {
        const float cy = s_c[off], sy = s_s[off]; ++off;
#pragma unroll
        for (int k0 = 0; k0 < DIM; ++k0) {
          if (k0 & m) continue;
          const int k1 = k0 | m;
          const float ar = vr[k0], ai = vi[k0], br = vr[k1], bi = vi[k1];
          vr[k0] = cy * ar - sy * br;  vi[k0] = cy * ai - sy * bi;
          vr[k1] = sy * ar + cy * br;  vi[k1] = sy * ai + cy * bi;
        }
      }
    }
    // --- entangler: CNOT(0,1), CNOT(1,2), CNOT(2,3), CNOT(3,0), applied in
    // this order as left-multiplications (reduce(lambda A,B: B@A, ...)).
    // Left-mult by CNOT(a,b): v'[r] = v[r ^ ((r>>ca)&1)<<tb] -> swap pairs.
#pragma unroll
    for (int g = 0; g < 4; ++g) {
      const int a = (g < 3) ? g : 3;
      const int b = (g < 3) ? (g + 1) : 0;
      const int ca = 1 << (3 - a);
      const int tb = 1 << (3 - b);
#pragma unroll
      for (int r = 0; r < DIM; ++r) {
        if ((r & ca) && !(r & tb)) {
          const int r2 = r | tb;
          float tmp;
          tmp = vr[r]; vr[r] = vr[r2]; vr[r2] = tmp;
          tmp = vi[r]; vi[r] = vi[r2]; vi[r2] = tmp;
        }
      }
    }
  }
  // vr/vi hold column `col` of U: U[k][col]
#pragma unroll
  for (int k = 0; k < DIM; ++k) {
    Uout[k * DIM + col]       = vr[k];
    Uout[256 + k * DIM + col] = vi[k];
  }
}

// ---------------------------------------------------------------------------
// Kernel B: one thread per patch. psi0 = product state from 4 RY-encoded
// pixels; psi = U * psi0 (complex 16x16 x real vec); probs -> signed sums.
// U accesses are wave-uniform -> scalar loads expected.
// ---------------------------------------------------------------------------
__global__ __launch_bounds__(256) void quanv_kernel(
    const float* __restrict__ x, const float* __restrict__ U,
    float* __restrict__ out, int npatch) {
  const int n = blockIdx.x * 256 + threadIdx.x;  // global patch id
  if (n >= npatch) return;
  const unsigned b  = (unsigned)n / 196u;
  const unsigned p  = (unsigned)n - b * 196u;
  const unsigned r1 = p / 14u;
  const unsigned c1 = p - r1 * 14u;
  // patch pixels: x[b*784 + (2*r1 + r2)*28 + (2*c1 + c2)], order (r2,c2)
  const float* xb = x + b * 784u + r1 * 56u + c1 * 2u;
  const float2 t0 = *(const float2*)(xb);       // (0,0), (0,1)
  const float2 t1 = *(const float2*)(xb + 28);  // (1,0), (1,1)

  const float HPI = 1.57079632679489662f;  // theta/2 = px * pi/2
  float c0, s0, c1q, s1q, c2q, s2q, c3q, s3q;
  __sincosf(t0.x * HPI, &s0,  &c0);
  __sincosf(t0.y * HPI, &s1q, &c1q);
  __sincosf(t1.x * HPI, &s2q, &c2q);
  __sincosf(t1.y * HPI, &s3q, &c3q);

  // psi0[k] = prod_q (bit_{3-q}(k) ? sin_q : cos_q); split as (q0,q1)x(q2,q3)
  const float ab[4] = {c0 * c1q, c0 * s1q, s0 * c1q, s0 * s1q};
  const float cd[4] = {c2q * c3q, c2q * s3q, s2q * c3q, s2q * s3q};
  float psi0[16];
#pragma unroll
  for (int k = 0; k < 16; ++k) psi0[k] = ab[k >> 2] * cd[k & 3];

  const float* __restrict__ Ur = U;
  const float* __restrict__ Ui = U + 256;
  float ev0 = 0.f, ev1 = 0.f, ev2 = 0.f, ev3 = 0.f;
#pragma unroll
  for (int j = 0; j < 16; ++j) {
    float pr = 0.f, pi = 0.f;
#pragma unroll
    for (int k = 0; k < 16; ++k) {
      pr = fmaf(Ur[j * 16 + k], psi0[k], pr);
      pi = fmaf(Ui[j * 16 + k], psi0[k], pi);
    }
    const float prob = fmaf(pr, pr, pi * pi);
    // ZS signs: zs[j][i] = 1 - 2*bit(3-i of j); compile-time per unrolled j
    ev0 += (j & 8) ? -prob : prob;
    ev1 += (j & 4) ? -prob : prob;
    ev2 += (j & 2) ? -prob : prob;
    ev3 += (j & 1) ? -prob : prob;
  }
  // out flat index = b*784 + p*4 + i = n*4 + i -> one float4 store
  ((float4*)out)[n] = make_float4(ev0, ev1, ev2, ev3);
}

// ---------------------------------------------------------------------------
extern "C" void kernel_launch(void* const* d_in, const int* in_sizes, int n_in,
                              void* d_out, int out_size, void* d_ws, size_t ws_size,
                              hipStream_t stream) {
  const float* x      = (const float*)d_in[0];   // [4096, 784] fp32
  const float* params = (const float*)d_in[1];   // [36] fp32
  float* out = (float*)d_out;                    // [4096, 784] fp32
  float* U   = (float*)d_ws;                     // 512 floats scratch

  build_unitary_kernel<<<1, 64, 0, stream>>>(params, U);

  const int npatch = in_sizes[0] / 4;            // 4096*196 = 802816
  const int nblk = (npatch + 255) / 256;
  quanv_kernel<<<nblk, 256, 0, stream>>>(x, U, out, npatch);
}

// Round 2
// 78.923 us; speedup vs baseline: 1.0694x; 1.0694x over previous
//
#include <hip/hip_runtime.h>
#include <math.h>

#define DIM 16

typedef __attribute__((ext_vector_type(8))) _Float16 half8;
typedef __attribute__((ext_vector_type(16))) float f32x16;

// ---------------------------------------------------------------------------
// Kernel A: build the 16x16 variational unitary from params[36].
// Lane c evolves basis column c in registers. Output layout = MFMA B-matrix:
//   Bmat[k][n] (fp32, [16][32] row-major), n<16: Re U[n][k], n>=16: Im U[n-16][k]
// (lane c holds U[:,c] => writes row k=c: Bmat[c*32+n] = vr[n] / vi[n-16]).
// ---------------------------------------------------------------------------
__global__ __launch_bounds__(64) void build_unitary_kernel(
    const float* __restrict__ params, float* __restrict__ Bmat) {
  __shared__ float s_c[36], s_s[36];
  const int t = threadIdx.x;
  if (t < 36) {
    const float half = params[t] * 0.5f;
    s_c[t] = cosf(half);
    s_s[t] = sinf(half);
  }
  __syncthreads();
  if (t >= DIM) return;
  const int col = t;

  float vr[DIM], vi[DIM];
#pragma unroll
  for (int k = 0; k < DIM; ++k) { vr[k] = (k == col) ? 1.0f : 0.0f; vi[k] = 0.0f; }

  int off = 0;
#pragma unroll
  for (int layer = 0; layer < 3; ++layer) {
#pragma unroll
    for (int w = 0; w < 4; ++w) {
      const int m = 1 << (3 - w);  // wire w <-> bit (3-w), big-endian
      {  // RY
        const float cy = s_c[off], sy = s_s[off]; ++off;
#pragma unroll
        for (int k0 = 0; k0 < DIM; ++k0) {
          if (k0 & m) continue;
          const int k1 = k0 | m;
          const float ar = vr[k0], ai = vi[k0], br = vr[k1], bi = vi[k1];
          vr[k0] = cy * ar - sy * br;  vi[k0] = cy * ai - sy * bi;
          vr[k1] = sy * ar + cy * br;  vi[k1] = sy * ai + cy * bi;
        }
      }
      {  // RZ: diag(e^{-it/2}, e^{+it/2})
        const float cz = s_c[off], sz = s_s[off]; ++off;
#pragma unroll
        for (int k = 0; k < DIM; ++k) {
          const float sg = (k & m) ? sz : -sz;
          const float ar = vr[k], ai = vi[k];
          vr[k] = cz * ar - sg * ai;
          vi[k] = cz * ai + sg * ar;
        }
      }
      {  // RY
        const float cy = s_c[off], sy = s_s[off]; ++off;
#pragma unroll
        for (int k0 = 0; k0 < DIM; ++k0) {
          if (k0 & m) continue;
          const int k1 = k0 | m;
          const float ar = vr[k0], ai = vi[k0], br = vr[k1], bi = vi[k1];
          vr[k0] = cy * ar - sy * br;  vi[k0] = cy * ai - sy * bi;
          vr[k1] = sy * ar + cy * br;  vi[k1] = sy * ai + cy * bi;
        }
      }
    }
    // entangler: CNOT(0,1),(1,2),(2,3),(3,0) as left-mults (row swaps)
#pragma unroll
    for (int g = 0; g < 4; ++g) {
      const int a = (g < 3) ? g : 3;
      const int b = (g < 3) ? (g + 1) : 0;
      const int ca = 1 << (3 - a);
      const int tb = 1 << (3 - b);
#pragma unroll
      for (int r = 0; r < DIM; ++r) {
        if ((r & ca) && !(r & tb)) {
          const int r2 = r | tb;
          float tmp;
          tmp = vr[r]; vr[r] = vr[r2]; vr[r2] = tmp;
          tmp = vi[r]; vi[r] = vi[r2]; vi[r2] = tmp;
        }
      }
    }
  }
#pragma unroll
  for (int n = 0; n < DIM; ++n) {
    Bmat[col * 32 + n]       = vr[n];
    Bmat[col * 32 + 16 + n]  = vi[n];
  }
}

// ---------------------------------------------------------------------------
// Kernel B: MFMA path. Per wave-iteration: 32 patches.
//   A[m][k] = psi0[patch m][k]  (lane l: m=l&31, k = 8*(l>>5)+j, j=0..7)
//   B[k][n] = U[n][k] re/im stacked (loaded ONCE -> registers)
//   C[m][n] = Re psi (n<16) / Im psi (n>=16), fp32 accum.
// hi/lo f16 split (3 MFMAs) keeps error at fp32 level.
// Epilogue: q=C^2 -> LDS[row][36] -> 1 thread/patch: probs, signed WHT sums.
// ---------------------------------------------------------------------------
__global__ __launch_bounds__(256) void quanv_mfma_kernel(
    const float* __restrict__ x, const float* __restrict__ Bmat,
    float* __restrict__ out, int npatch) {
  __shared__ __align__(16) float q_lds[256 * 36];  // 36 KB

  const int tid  = threadIdx.x;
  const int lane = tid & 63;
  const int wave = tid >> 6;
  const int nl   = lane & 31;   // A-row (patch in batch) / B-col
  const int h    = lane >> 5;   // k-half
  const int kb   = h * 8;

  // ---- B fragment: load U once, split hi/lo f16 ----
  half8 bh, bl;
#pragma unroll
  for (int j = 0; j < 8; ++j) {
    const float v = Bmat[(kb + j) * 32 + nl];
    const _Float16 vh = (_Float16)v;
    bh[j] = vh;
    bl[j] = (_Float16)(v - (float)vh);
  }

  const int blk_base = blockIdx.x * 256;

#pragma unroll
  for (int it = 0; it < 2; ++it) {
    const int roff = wave * 64 + it * 32;       // patch offset within block
    int n = blk_base + roff + nl;               // global patch id
    if (n >= npatch) n = npatch - 1;            // clamp (grid divides exactly)
    const unsigned nu = (unsigned)n;
    const unsigned b  = nu / 196u;
    const unsigned p  = nu - b * 196u;
    const unsigned r1 = p / 14u;
    const unsigned c1 = p - r1 * 14u;
    const float* xb = x + b * 784u + r1 * 56u + c1 * 2u;
    const float2 t0 = *(const float2*)(xb);       // (0,0),(0,1)
    const float2 t1 = *(const float2*)(xb + 28);  // (1,0),(1,1)

    const float HPI = 1.57079632679489662f;  // theta/2 = px*pi/2
    float c0, s0, c1q, s1q, c2q, s2q, c3q, s3q;
    __sincosf(t0.x * HPI, &s0,  &c0);
    __sincosf(t0.y * HPI, &s1q, &c1q);
    __sincosf(t1.x * HPI, &s2q, &c2q);
    __sincosf(t1.y * HPI, &s3q, &c3q);

    // psi0[k] = prod over qubits; this lane holds k = kb..kb+7
    // bit3(k)=h -> factor (h? s0 : c0); bit2 -> q1; bits1,0 -> q2,q3
    const float f   = h ? s0 : c0;
    const float ab0 = f * c1q, ab1 = f * s1q;
    const float cd[4] = {c2q * c3q, c2q * s3q, s2q * c3q, s2q * s3q};

    half8 ah, al;
#pragma unroll
    for (int j = 0; j < 8; ++j) {
      const float v = ((j & 4) ? ab1 : ab0) * cd[j & 3];
      const _Float16 vh = (_Float16)v;
      ah[j] = vh;
      al[j] = (_Float16)(v - (float)vh);
    }

    f32x16 C;
#pragma unroll
    for (int r = 0; r < 16; ++r) C[r] = 0.0f;
    C = __builtin_amdgcn_mfma_f32_32x32x16_f16(ah, bh, C, 0, 0, 0);
    C = __builtin_amdgcn_mfma_f32_32x32x16_f16(al, bh, C, 0, 0, 0);
    C = __builtin_amdgcn_mfma_f32_32x32x16_f16(ah, bl, C, 0, 0, 0);

    // q = C^2 -> LDS. C/D layout: col=lane&31, row=(reg&3)+8*(reg>>2)+4*h.
    // stride 36: bank (4*row+col)%32 -> each bank exactly 2x per store = free
#pragma unroll
    for (int reg = 0; reg < 16; ++reg) {
      const int row = (reg & 3) + 8 * (reg >> 2) + 4 * h + roff;
      q_lds[row * 36 + nl] = C[reg] * C[reg];
    }
  }
  __syncthreads();

  // ---- epilogue: thread t = patch blk_base + t ----
  float q[32];
#pragma unroll
  for (int j = 0; j < 8; ++j) {
    const float4 v = *(const float4*)&q_lds[tid * 36 + 4 * j];
    q[4 * j + 0] = v.x; q[4 * j + 1] = v.y;
    q[4 * j + 2] = v.z; q[4 * j + 3] = v.w;
  }
  float pr[16];
#pragma unroll
  for (int j = 0; j < 16; ++j) pr[j] = q[j] + q[j + 16];  // |psi_j|^2

  // signed sums via fast-WHT: ev_i uses sign bit (3-i) of j
  float s1[8], d1[8];
#pragma unroll
  for (int j = 0; j < 8; ++j) { s1[j] = pr[j] + pr[j + 8]; d1[j] = pr[j] - pr[j + 8]; }
  float ev0 = ((d1[0] + d1[1]) + (d1[2] + d1[3])) + ((d1[4] + d1[5]) + (d1[6] + d1[7]));
  float s2[4], d2[4];
#pragma unroll
  for (int j = 0; j < 4; ++j) { s2[j] = s1[j] + s1[j + 4]; d2[j] = s1[j] - s1[j + 4]; }
  float ev1 = (d2[0] + d2[1]) + (d2[2] + d2[3]);
  const float s3a = s2[0] + s2[2], s3b = s2[1] + s2[3];
  const float d3a = s2[0] - s2[2], d3b = s2[1] - s2[3];
  float ev2 = d3a + d3b;
  float ev3 = (s3a + s3b) - 2.0f * s3b;  // = s3even - s3odd
  // (s3a = sum over even j, s3b = sum over odd j)
  ev3 = s3a - s3b;

  const int gp = blk_base + tid;
  if (gp < npatch) ((float4*)out)[gp] = make_float4(ev0, ev1, ev2, ev3);
}

// ---------------------------------------------------------------------------
extern "C" void kernel_launch(void* const* d_in, const int* in_sizes, int n_in,
                              void* d_out, int out_size, void* d_ws, size_t ws_size,
                              hipStream_t stream) {
  const float* x      = (const float*)d_in[0];   // [4096, 784] fp32
  const float* params = (const float*)d_in[1];   // [36] fp32
  float* out  = (float*)d_out;                   // [4096, 784] fp32
  float* Bmat = (float*)d_ws;                    // 512 floats scratch

  build_unitary_kernel<<<1, 64, 0, stream>>>(params, Bmat);

  const int npatch = in_sizes[0] / 4;            // 4096*196 = 802816
  const int nblk = (npatch + 255) / 256;         // 3136
  quanv_mfma_kernel<<<nblk, 256, 0, stream>>>(x, Bmat, out, npatch);
}

// Round 3
// 76.537 us; speedup vs baseline: 1.1028x; 1.0312x over previous
//
#include <hip/hip_runtime.h>
#include <math.h>

#define DIM 16

typedef __attribute__((ext_vector_type(8))) _Float16 half8;
typedef __attribute__((ext_vector_type(16))) float f32x16;

// ---------------------------------------------------------------------------
// Kernel A: build the 16x16 variational unitary from params[36].
// Lane c evolves basis column c in registers. Output layout = MFMA A-matrix:
//   Amat[m][k] fp32 [32][16] row-major; m<16: Re U[m][k], m>=16: Im U[m-16][k]
// (lane c holds U[:,c] => Amat[n*16+c] = vr[n], Amat[(16+n)*16+c] = vi[n]).
// ---------------------------------------------------------------------------
__global__ __launch_bounds__(64) void build_unitary_kernel(
    const float* __restrict__ params, float* __restrict__ Amat) {
  __shared__ float s_c[36], s_s[36];
  const int t = threadIdx.x;
  if (t < 36) {
    const float half = params[t] * 0.5f;
    s_c[t] = cosf(half);
    s_s[t] = sinf(half);
  }
  __syncthreads();
  if (t >= DIM) return;
  const int col = t;

  float vr[DIM], vi[DIM];
#pragma unroll
  for (int k = 0; k < DIM; ++k) { vr[k] = (k == col) ? 1.0f : 0.0f; vi[k] = 0.0f; }

  int off = 0;
#pragma unroll
  for (int layer = 0; layer < 3; ++layer) {
#pragma unroll
    for (int w = 0; w < 4; ++w) {
      const int m = 1 << (3 - w);  // wire w <-> bit (3-w), big-endian
      {  // RY
        const float cy = s_c[off], sy = s_s[off]; ++off;
#pragma unroll
        for (int k0 = 0; k0 < DIM; ++k0) {
          if (k0 & m) continue;
          const int k1 = k0 | m;
          const float ar = vr[k0], ai = vi[k0], br = vr[k1], bi = vi[k1];
          vr[k0] = cy * ar - sy * br;  vi[k0] = cy * ai - sy * bi;
          vr[k1] = sy * ar + cy * br;  vi[k1] = sy * ai + cy * bi;
        }
      }
      {  // RZ: diag(e^{-it/2}, e^{+it/2})
        const float cz = s_c[off], sz = s_s[off]; ++off;
#pragma unroll
        for (int k = 0; k < DIM; ++k) {
          const float sg = (k & m) ? sz : -sz;
          const float ar = vr[k], ai = vi[k];
          vr[k] = cz * ar - sg * ai;
          vi[k] = cz * ai + sg * ar;
        }
      }
      {  // RY
        const float cy = s_c[off], sy = s_s[off]; ++off;
#pragma unroll
        for (int k0 = 0; k0 < DIM; ++k0) {
          if (k0 & m) continue;
          const int k1 = k0 | m;
          const float ar = vr[k0], ai = vi[k0], br = vr[k1], bi = vi[k1];
          vr[k0] = cy * ar - sy * br;  vi[k0] = cy * ai - sy * bi;
          vr[k1] = sy * ar + cy * br;  vi[k1] = sy * ai + cy * bi;
        }
      }
    }
    // entangler: CNOT(0,1),(1,2),(2,3),(3,0) as left-mults (row swaps)
#pragma unroll
    for (int g = 0; g < 4; ++g) {
      const int a = (g < 3) ? g : 3;
      const int b = (g < 3) ? (g + 1) : 0;
      const int ca = 1 << (3 - a);
      const int tb = 1 << (3 - b);
#pragma unroll
      for (int r = 0; r < DIM; ++r) {
        if ((r & ca) && !(r & tb)) {
          const int r2 = r | tb;
          float tmp;
          tmp = vr[r]; vr[r] = vr[r2]; vr[r2] = tmp;
          tmp = vi[r]; vi[r] = vi[r2]; vi[r2] = tmp;
        }
      }
    }
  }
#pragma unroll
  for (int n = 0; n < DIM; ++n) {
    Amat[n * 16 + col]        = vr[n];
    Amat[(16 + n) * 16 + col] = vi[n];
  }
}

// ---------------------------------------------------------------------------
// Kernel B: no-LDS MFMA path. Per wave-iteration: 32 patches.
//   A[m][k] = [Re U; Im U] rows (loaded ONCE, hi/lo f16 split -> ~fp32 prec)
//   B[k][n] = psi0[k][patch n]  (per-patch, plain f16; lane l: n=l&31,
//             k = 8*(l>>5)+j)
//   C[m][n]: lane l holds, for its OWN patch n=l&31, rows
//            m = (reg&3)+8*(reg>>2)+4h (re) and m+16 (im), h=l>>5.
// probs + signed ZS sums fully in-register (signs are functions of reg/h);
// halves combined with 4 shfl_xor(32). No LDS, no barrier.
// ---------------------------------------------------------------------------
__global__ __launch_bounds__(256) void quanv_mfma_kernel(
    const float* __restrict__ x, const float* __restrict__ Amat,
    float* __restrict__ out, int npatch) {
  const int tid  = threadIdx.x;
  const int lane = tid & 63;
  const int wave = tid >> 6;
  const int nl   = lane & 31;   // A-row m (U row) / C-col (patch in batch)
  const int h    = lane >> 5;   // k-half

  // ---- A fragment: U rows, loaded once, hi/lo f16 split ----
  const float4* Arow = (const float4*)(Amat + nl * 16 + 8 * h);
  const float4 ua = Arow[0];
  const float4 ub = Arow[1];
  const float uf[8] = {ua.x, ua.y, ua.z, ua.w, ub.x, ub.y, ub.z, ub.w};
  half8 Uh, Ul;
#pragma unroll
  for (int j = 0; j < 8; ++j) {
    const _Float16 vh = (_Float16)uf[j];
    Uh[j] = vh;
    Ul[j] = (_Float16)(uf[j] - (float)vh);
  }

  const int base = blockIdx.x * 256 + wave * 64;

#pragma unroll
  for (int it = 0; it < 2; ++it) {
    int n = base + it * 32 + nl;       // patch id (lanes l and l+32: same patch)
    if (n >= npatch) n = npatch - 1;   // safety clamp (grid divides exactly)
    const unsigned nu = (unsigned)n;
    const unsigned b  = nu / 196u;
    const unsigned p  = nu - b * 196u;
    const unsigned r1 = p / 14u;
    const unsigned c1 = p - r1 * 14u;
    const float* xb = x + b * 784u + r1 * 56u + c1 * 2u;
    const float2 t0 = *(const float2*)(xb);       // (0,0),(0,1)
    const float2 t1 = *(const float2*)(xb + 28);  // (1,0),(1,1)

    const float HPI = 1.57079632679489662f;  // theta/2 = px*pi/2
    float c0, s0, c1q, s1q, c2q, s2q, c3q, s3q;
    __sincosf(t0.x * HPI, &s0,  &c0);
    __sincosf(t0.y * HPI, &s1q, &c1q);
    __sincosf(t1.x * HPI, &s2q, &c2q);
    __sincosf(t1.y * HPI, &s3q, &c3q);

    // B-frag: b[j] = psi0[k=8h+j] of own patch; bit3(k)=h -> (h? s0 : c0)
    const float f   = h ? s0 : c0;
    const float ab0 = f * c1q, ab1 = f * s1q;
    const float cd[4] = {c2q * c3q, c2q * s3q, s2q * c3q, s2q * s3q};
    half8 bfrag;
#pragma unroll
    for (int j = 0; j < 8; ++j)
      bfrag[j] = (_Float16)(((j & 4) ? ab1 : ab0) * cd[j & 3]);

    f32x16 C;
#pragma unroll
    for (int r = 0; r < 16; ++r) C[r] = 0.0f;
    C = __builtin_amdgcn_mfma_f32_32x32x16_f16(Uh, bfrag, C, 0, 0, 0);
    C = __builtin_amdgcn_mfma_f32_32x32x16_f16(Ul, bfrag, C, 0, 0, 0);

    // probs: reg r=0..7 -> j = (r&3) + 4h + 8*(r>>2); re=C[r], im=C[r+8]
    float pq[8];
#pragma unroll
    for (int r = 0; r < 8; ++r) pq[r] = fmaf(C[r], C[r], C[r + 8] * C[r + 8]);

    // signed sums: j bits: bit3=(r>>2), bit2=h, bit1=(r>>1)&1, bit0=r&1
    const float s03 = pq[0] + pq[3], s12 = pq[1] + pq[2];
    const float s47 = pq[4] + pq[7], s56 = pq[5] + pq[6];
    float e0 = (s03 + s12) - (s47 + s56);                          // bit3
    float e1 = (s03 + s12) + (s47 + s56);  e1 = h ? -e1 : e1;      // bit2 = h
    float e2 = ((pq[0] + pq[1]) - (pq[2] + pq[3]))
             + ((pq[4] + pq[5]) - (pq[6] + pq[7]));                // bit1
    float e3 = ((pq[0] - pq[1]) + (pq[2] - pq[3]))
             + ((pq[4] - pq[5]) + (pq[6] - pq[7]));                // bit0
    // combine the two k-halves (lane l <-> l^32)
    e0 += __shfl_xor(e0, 32, 64);
    e1 += __shfl_xor(e1, 32, 64);
    e2 += __shfl_xor(e2, 32, 64);
    e3 += __shfl_xor(e3, 32, 64);

    if (h == 0 && n < npatch)
      ((float4*)out)[n] = make_float4(e0, e1, e2, e3);
  }
}

// ---------------------------------------------------------------------------
extern "C" void kernel_launch(void* const* d_in, const int* in_sizes, int n_in,
                              void* d_out, int out_size, void* d_ws, size_t ws_size,
                              hipStream_t stream) {
  const float* x      = (const float*)d_in[0];   // [4096, 784] fp32
  const float* params = (const float*)d_in[1];   // [36] fp32
  float* out  = (float*)d_out;                   // [4096, 784] fp32
  float* Amat = (float*)d_ws;                    // 512 floats scratch

  build_unitary_kernel<<<1, 64, 0, stream>>>(params, Amat);

  const int npatch = in_sizes[0] / 4;            // 4096*196 = 802816
  const int nblk = (npatch + 255) / 256;         // 3136
  quanv_mfma_kernel<<<nblk, 256, 0, stream>>>(x, Amat, out, npatch);
}